// Round 6
// baseline (252.640 us; speedup 1.0000x reference)
//
#include <hip/hip_runtime.h>
#include <hip/hip_bf16.h>

typedef __bf16 bf16_t;
typedef __bf16 bf16x8 __attribute__((ext_vector_type(8)));
typedef float f32x4 __attribute__((ext_vector_type(4)));

typedef const __attribute__((address_space(3))) bf16_t* lds_cptr;

// ---------------------------------------------------------------------------
// fused fp32 -> bf16 cast for 3 arrays (one launch; memory-bound)
// ---------------------------------------------------------------------------
__global__ __launch_bounds__(256) void cast3_f32_to_bf16(
    const float* __restrict__ a, bf16_t* __restrict__ ao, int na8,
    const float* __restrict__ b, bf16_t* __restrict__ bo, int nb8,
    const float* __restrict__ c, bf16_t* __restrict__ co, int nc8) {
  int i = blockIdx.x * blockDim.x + threadIdx.x;
  const float* in;
  bf16_t* out;
  int j;
  if (i < na8) {
    in = a; out = ao; j = i;
  } else if (i < na8 + nb8) {
    in = b; out = bo; j = i - na8;
  } else if (i < na8 + nb8 + nc8) {
    in = c; out = co; j = i - na8 - nb8;
  } else {
    return;
  }
  const float4* in4 = (const float4*)in;
  float4 f0 = in4[2 * j];
  float4 f1 = in4[2 * j + 1];
  bf16x8 o;
  o[0] = (bf16_t)f0.x; o[1] = (bf16_t)f0.y;
  o[2] = (bf16_t)f0.z; o[3] = (bf16_t)f0.w;
  o[4] = (bf16_t)f1.x; o[5] = (bf16_t)f1.y;
  o[6] = (bf16_t)f1.z; o[7] = (bf16_t)f1.w;
  ((bf16x8*)out)[j] = o;
}

// ---------------------------------------------------------------------------
// async global->LDS, 16B per lane. LDS dest = wave-uniform base + lane*16.
// ---------------------------------------------------------------------------
__device__ __forceinline__ void gload_lds16(const bf16_t* g, bf16_t* l) {
  __builtin_amdgcn_global_load_lds(
      (const __attribute__((address_space(1))) void*)g,
      (__attribute__((address_space(3))) void*)l,
      16, 0, 0);
}

// No "memory" clobber on waitcnt asm (a clobber re-attracts a compiler
// vmcnt(0) DMA drain -- round-3 lesson, -14us). Ordering: volatile asm
// mutual program order + sched_barrier(0) fences for MFMA (rule #18).
template <int N>
__device__ __forceinline__ void vmwait() {
  asm volatile("s_waitcnt vmcnt(%0)" :: "i"(N));
}

template <int N>
__device__ __forceinline__ void lgkmwait() {
  asm volatile("s_waitcnt lgkmcnt(%0)" :: "i"(N));
}

// inline-asm ds_read_b128 batch: dst[I] <- LDS[p + I*STRIDE_B bytes].
template <int I, int N, int STRIDE_B>
__device__ __forceinline__ void ldsr_n(bf16x8* dst, lds_cptr p) {
  if constexpr (I < N) {
    asm volatile("ds_read_b128 %0, %1 offset:%2"
                 : "=v"(dst[I]) : "v"(p), "i"(I * STRIDE_B));
    ldsr_n<I + 1, N, STRIDE_B>(dst, p);
  }
}

// MFMA row-groups with counted lgkm gates: group i waits lgkmcnt(BASE-I).
// DS reads complete in-order per wave, so the count releases exactly the
// fragment needed while later reads drain UNDER the MFMAs.
template <int I, int FR, int FC, int BASE>
__device__ __forceinline__ void mfma_gated(const bf16x8* aq, const bf16x8* bq,
                                           f32x4 (&acc)[FR][FC]) {
  if constexpr (I < FR) {
    lgkmwait<BASE - I>();
    __builtin_amdgcn_sched_barrier(0);
#pragma unroll
    for (int j = 0; j < FC; ++j)
      acc[I][j] = __builtin_amdgcn_mfma_f32_16x16x32_bf16(
          aq[I], bq[j], acc[I][j], 0, 0, 0);
    mfma_gated<I + 1, FR, FC, BASE>(aq, bq, acc);
  }
}

// ---------------------------------------------------------------------------
// Pipelined GEMM: C[M,N] = A[M,K]*B[N,K]^T + bias[N], optional fused swish.
// BM=256 x BN=128 tile, BK=64 bodies, 512 threads (8 waves, 4Mx2N ->
// 64x64 per wave, FR=FC=4), 16x16x32 bf16 MFMA, 3 rotating LDS buffers
// (144 KiB), stage prefetch depth 2 bodies. ONE barrier + ONE counted
// vmcnt per K=64 (round-6 change: halves sync overhead per FLOP vs BK=32,
// and BN=128/WM=4 cuts LDS read redundancy 96->64 KB per K=32-equiv).
// Per body s (read buf r=s%3, stage s+2 into buf (s+2)%3):
//   ds_read khalf0 (B,A = 8), stage (6 gloads), ds_read khalf1 (8);
//   setprio(1); khalf0 groups gated lgkm 11..8; khalf1 gated 3..0
//   (final gate = lgkmcnt(0) -> buf reads drained = overwrite safety);
//   setprio(0); vmcnt(VMN=6) -> forces stage(s+1), issued a full body
//   (~2 bodies of slack from issue to deadline) earlier; s_barrier.
// Tail stages wrap mod NSB into not-read-again buffers (uniform counts).
// LDS rows are 64 elems (128 B); 16B-chunk swizzle phys = chunk ^ (row&7)
// (8 phys slots -> 2 lanes/bank pair = free); staged linearly via
// pre-swizzled per-lane global source column. Fragment-read xor term is
// lane-constant (fr&7); k-half-1 pointer = khalf0 pointer ^ 64 bytes.
// Requires: M%256==0, N%128==0, K%128==0.
// ---------------------------------------------------------------------------
#define BODY(rA_, rB_, wA_, wB_, sw_)                                         \
  {                                                                           \
    lds_cptr pa0 = (lds_cptr)(sA + (rA_)) + aoff0;                            \
    lds_cptr pb0 = (lds_cptr)(sB + (rB_)) + boff0;                            \
    lds_cptr pa1 = (lds_cptr)(sA + (rA_)) + aoff1;                            \
    lds_cptr pb1 = (lds_cptr)(sB + (rB_)) + boff1;                            \
    bf16x8 b0[FC], a0[FR], b1[FC], a1[FR];                                    \
    ldsr_n<0, FC, 2048>(b0, pb0);                                             \
    ldsr_n<0, FR, 2048>(a0, pa0);                                             \
    stageA(sw_, wA_);                                                         \
    stageB(sw_, wB_);                                                         \
    ldsr_n<0, FC, 2048>(b1, pb1);                                             \
    ldsr_n<0, FR, 2048>(a1, pa1);                                             \
    __builtin_amdgcn_s_setprio(1);                                            \
    mfma_gated<0, FR, FC, FR + FC + FR - 1>(a0, b0, acc);                     \
    mfma_gated<0, FR, FC, FR - 1>(a1, b1, acc);                               \
    __builtin_amdgcn_s_setprio(0);                                            \
    vmwait<VMN>();                                                            \
    __builtin_amdgcn_s_barrier();                                             \
  }

template <bool SWISH>
__global__ __launch_bounds__(512, 2) void gemm_bt64(
    const bf16_t* __restrict__ A, const bf16_t* __restrict__ B,
    const float* __restrict__ bias, void* __restrict__ Cout,
    int M, int N, int K, int XW, int px, int py) {
  constexpr int BM = 256, BN = 128, BK = 64;
  constexpr int FR = 4, FC = 4;          // 64x64 per wave (4Mx2N waves)
  constexpr int ACALLS = BM / 64;        // 4 gloads per A stage
  constexpr int BCALLS = BN / 64;        // 2 gloads per B stage
  constexpr int VMN = ACALLS + BCALLS;   // 6 = one body's stage in flight
  constexpr int SA_SZ = BM * BK;         // 16384 elems / buffer
  constexpr int SB_SZ = BN * BK;         // 8192 elems / buffer

  const int tid = threadIdx.x;
  const int wave = tid >> 6;
  const int lane = tid & 63;

  // ---- XCD-aware block swizzle (grid % 8 == 0 in both uses) ----
  const int bid = blockIdx.x;
  const int xcd = bid & 7;
  const int idx = bid >> 3;
  const int cx = xcd % XW;
  const int cy = xcd / XW;
  const int bx = cx * px + idx % px;
  const int by = cy * py + idx / px;
  const int tileM = by * BM;
  const int tileN = bx * BN;

  __shared__ __align__(16) bf16_t sA[3 * SA_SZ];
  __shared__ __align__(16) bf16_t sB[3 * SB_SZ];

  // ---- staging geometry: one call = 512 thr x 16B = 64 rows x 64 cols ----
  // lane -> row (lane>>3), phys chunk slot (lane&7) (linear LDS dest);
  // fetches GLOBAL chunk (lane&7) ^ (row&7)  [row&7 = (lane>>3)&7]
  const int srow = (wave << 3) + (lane >> 3);              // 0..63
  const int sgc = ((lane & 7) ^ ((lane >> 3) & 7)) << 3;   // global col elems
  const bf16_t* gA = A + (size_t)(tileM + srow) * K + sgc;
  const bf16_t* gB = B + (size_t)(tileN + srow) * K + sgc;

  auto stageA = [&](int s, int wb) {
    bf16_t* l = sA + wb + (wave << 9);  // wave-uniform base (wave*8 rows)
    const bf16_t* g = gA + s * BK;
#pragma unroll
    for (int c = 0; c < ACALLS; ++c)
      gload_lds16(g + (size_t)(c * 64) * K, l + c * 4096);
  };
  auto stageB = [&](int s, int wb) {
    bf16_t* l = sB + wb + (wave << 9);
    const bf16_t* g = gB + s * BK;
#pragma unroll
    for (int c = 0; c < BCALLS; ++c)
      gload_lds16(g + (size_t)(c * 64) * K, l + c * 4096);
  };

  // ---- fragment read offsets (elems, within one buffer) ----
  const int wr = wave >> 1;            // 0..3 (M dim)
  const int wc = wave & 1;             // 0..1 (N dim)
  const int fr = lane & 15;
  const int pc0 = (lane >> 4) ^ (fr & 7);          // swizzled phys chunk
  const int aoff0 = (wr * 64 + fr) * 64 + pc0 * 8;
  const int boff0 = (wc * 64 + fr) * 64 + pc0 * 8;
  const int aoff1 = aoff0 ^ 32;        // khalf1: phys ^= 4 -> elems ^= 32
  const int boff1 = boff0 ^ 32;

  f32x4 acc[FR][FC] = {};

  const int NSB = K >> 6;  // K=64 bodies; NSB >= 3

  // ---- prologue: stage bodies 0,1; force 0 complete; sync ----
  stageA(0, 0);          stageB(0, 0);
  stageA(1, SA_SZ);      stageB(1, SB_SZ);
  vmwait<VMN>();
  __builtin_amdgcn_s_barrier();

  // ---- main loop: rotate 3 buffers via uniform offsets (no dyn index) ----
  int rA = 0, rB = 0;
  int wA = 2 * SA_SZ, wB = 2 * SB_SZ;
  for (int s = 0; s < NSB; ++s) {
    int sw = s + 2;
    if (sw >= NSB) sw -= NSB;  // tail: wrapped stage into not-read-again buf
    BODY(rA, rB, wA, wB, sw)
    rA = (rA == 2 * SA_SZ) ? 0 : rA + SA_SZ;
    rB = (rB == 2 * SB_SZ) ? 0 : rB + SB_SZ;
    wA = (wA == 2 * SA_SZ) ? 0 : wA + SA_SZ;
    wB = (wB == 2 * SB_SZ) ? 0 : wB + SB_SZ;
  }

  // ---- epilogue: C/D layout col = lane&15, row = (lane>>4)*4 + reg ----
  // j INNERMOST: stores filling one cache line are adjacent so L2 merges
  // (round-5: WRITE_SIZE dropped to the ideal 64 MB).
  const int cRow0 = tileM + wr * 64 + ((lane >> 4) << 2);
  const int cCol0 = tileN + wc * 64 + (lane & 15);
  float bv[FC];
#pragma unroll
  for (int j = 0; j < FC; ++j) bv[j] = bias[cCol0 + j * 16];
#pragma unroll
  for (int i = 0; i < FR; ++i) {
#pragma unroll
    for (int r = 0; r < 4; ++r) {
      const size_t row = (size_t)(cRow0 + i * 16 + r);
#pragma unroll
      for (int j = 0; j < FC; ++j) {
        float h = acc[i][j][r] + bv[j];
        if constexpr (SWISH) {
          float h3 = h * h * h;
          float sw = h * (0.5f + 0.25f * h - 0.0208f * h3);
          ((bf16_t*)Cout)[row * N + cCol0 + j * 16] = (bf16_t)sw;
        } else {
          ((float*)Cout)[row * N + cCol0 + j * 16] = h;
        }
      }
    }
  }
}

// ---------------------------------------------------------------------------
// launch
// ---------------------------------------------------------------------------
extern "C" void kernel_launch(void* const* d_in, const int* in_sizes, int n_in,
                              void* d_out, int out_size, void* d_ws,
                              size_t ws_size, hipStream_t stream) {
  const float* X  = (const float*)d_in[0];  // [B,S,D] = [M,D]
  const float* W1 = (const float*)d_in[1];  // [F,D]
  const float* b1 = (const float*)d_in[2];  // [F]
  const float* W2 = (const float*)d_in[3];  // [D,F]
  const float* b2 = (const float*)d_in[4];  // [D]
  float* out = (float*)d_out;               // [M,D]

  const int F = in_sizes[2];      // 4096
  const int D = in_sizes[4];      // 1024
  const int M = in_sizes[0] / D;  // 8192

  // workspace layout (bf16): Xb[M*D] | W1b[F*D] | W2b[D*F] | SW[M*F]
  bf16_t* Xb  = (bf16_t*)d_ws;
  bf16_t* W1b = Xb + (size_t)M * D;
  bf16_t* W2b = W1b + (size_t)F * D;
  bf16_t* SW  = W2b + (size_t)D * F;

  const int nX = (M * D) / 8, nW1 = (F * D) / 8, nW2 = (D * F) / 8;
  const int nTot = nX + nW1 + nW2;
  cast3_f32_to_bf16<<<(nTot + 255) / 256, 256, 0, stream>>>(
      X, Xb, nX, W1, W1b, nW1, W2, W2b, nW2);

  // GEMM1: SW[M,F] = swish(Xb[M,D] @ W1b[F,D]^T + b1)   (bf16 out)
  // 256x128 tiles: gx = F/128 = 32, gy = M/256 = 32; XCDs as 4x2:
  // per-XCD patch 8x16, B-panel 8*128 cols * 1024 K * 2B = 2 MB L2-resident
  {
    const int gx = F / 128, gy = M / 256;
    const int XW = 4, XH = 2;
    const int px = gx / XW, py = gy / XH;
    gemm_bt64<true><<<gx * gy, 512, 0, stream>>>(
        Xb, W1b, b1, (void*)SW, M, F, D, XW, px, py);
  }

  // GEMM2: out[M,D] = SW[M,F] @ W2b[D,F]^T + b2         (fp32 out)
  // 256x128 tiles: gx = D/128 = 8, gy = M/256 = 32; XCDs as 2x4 -> 4x8 patch
  {
    const int gx = D / 128, gy = M / 256;
    const int XW = 2, XH = 4;
    const int px = gx / XW, py = gy / XH;
    gemm_bt64<false><<<gx * gy, 512, 0, stream>>>(
        SW, W2b, b2, (void*)out, M, D, F, XW, px, py);
  }
}

// Round 7
// 245.756 us; speedup vs baseline: 1.0280x; 1.0280x over previous
//
#include <hip/hip_runtime.h>
#include <hip/hip_bf16.h>

typedef __bf16 bf16_t;
typedef __bf16 bf16x8 __attribute__((ext_vector_type(8)));
typedef float f32x4 __attribute__((ext_vector_type(4)));

typedef const __attribute__((address_space(3))) bf16_t* lds_cptr;

// ---------------------------------------------------------------------------
// fused fp32 -> bf16 cast for 3 arrays (one launch; memory-bound)
// ---------------------------------------------------------------------------
__global__ __launch_bounds__(256) void cast3_f32_to_bf16(
    const float* __restrict__ a, bf16_t* __restrict__ ao, int na8,
    const float* __restrict__ b, bf16_t* __restrict__ bo, int nb8,
    const float* __restrict__ c, bf16_t* __restrict__ co, int nc8) {
  int i = blockIdx.x * blockDim.x + threadIdx.x;
  const float* in;
  bf16_t* out;
  int j;
  if (i < na8) {
    in = a; out = ao; j = i;
  } else if (i < na8 + nb8) {
    in = b; out = bo; j = i - na8;
  } else if (i < na8 + nb8 + nc8) {
    in = c; out = co; j = i - na8 - nb8;
  } else {
    return;
  }
  const float4* in4 = (const float4*)in;
  float4 f0 = in4[2 * j];
  float4 f1 = in4[2 * j + 1];
  bf16x8 o;
  o[0] = (bf16_t)f0.x; o[1] = (bf16_t)f0.y;
  o[2] = (bf16_t)f0.z; o[3] = (bf16_t)f0.w;
  o[4] = (bf16_t)f1.x; o[5] = (bf16_t)f1.y;
  o[6] = (bf16_t)f1.z; o[7] = (bf16_t)f1.w;
  ((bf16x8*)out)[j] = o;
}

// ---------------------------------------------------------------------------
// async global->LDS, 16B per lane. LDS dest = wave-uniform base + lane*16.
// ---------------------------------------------------------------------------
__device__ __forceinline__ void gload_lds16(const bf16_t* g, bf16_t* l) {
  __builtin_amdgcn_global_load_lds(
      (const __attribute__((address_space(1))) void*)g,
      (__attribute__((address_space(3))) void*)l,
      16, 0, 0);
}

// No "memory" clobber on waitcnt asm (a clobber re-attracts a compiler
// vmcnt(0) DMA drain -- round-3 lesson, -14us). Ordering: volatile asm
// mutual program order + sched_barrier(0) fences for MFMA (rule #18).
template <int N>
__device__ __forceinline__ void vmwait() {
  asm volatile("s_waitcnt vmcnt(%0)" :: "i"(N));
}

template <int N>
__device__ __forceinline__ void lgkmwait() {
  asm volatile("s_waitcnt lgkmcnt(%0)" :: "i"(N));
}

// inline-asm ds_read_b128 range: dst[I] <- LDS[p + I*1024 bytes], I in [S,E).
// (fragment row-block stride = 16 rows x 32 elems x 2B = 1024 B)
template <int I, int E>
__device__ __forceinline__ void ldsr_rng(bf16x8* dst, lds_cptr p) {
  if constexpr (I < E) {
    asm volatile("ds_read_b128 %0, %1 offset:%2"
                 : "=v"(dst[I]) : "v"(p), "i"(I * 1024));
    ldsr_rng<I + 1, E>(dst, p);
  }
}

// MFMA groups [I,END) gated by counted lgkm: group i waits lgkmcnt(BASE-i).
// Reads issue in order B[0..FC-1], A[0..FR-1]; group i needs FC+i+1 of its
// batch done. BASE = FR-1 when only the current batch is outstanding;
// BASE = FR+5 after the 6-read next-batch first half has been issued.
// DS reads complete in-order per wave, so the count releases exactly the
// fragment needed while later reads drain UNDER the MFMAs.
template <int I, int END, int FR, int FC, int BASE>
__device__ __forceinline__ void mfma_gr(const bf16x8 (&aq)[FR],
                                        const bf16x8 (&bq)[FC],
                                        f32x4 (&acc)[FR][FC]) {
  if constexpr (I < END) {
    lgkmwait<BASE - I>();
    __builtin_amdgcn_sched_barrier(0);
#pragma unroll
    for (int j = 0; j < FC; ++j)
      acc[I][j] = __builtin_amdgcn_mfma_f32_16x16x32_bf16(
          aq[I], bq[j], acc[I][j], 0, 0, 0);
    mfma_gr<I + 1, END, FR, FC, BASE>(aq, bq, acc);
  }
}

// ---------------------------------------------------------------------------
// Pipelined GEMM: C[M,N] = A[M,K]*B[N,K]^T + bias[N], optional fused swish.
// BM=256 x BN tile, 512 threads (8 waves), 16x16x32 bf16 MFMA.
// K in subtiles of 32, four LDS buffers (buf = s & 3), stage depth 3,
// and (round-7 change) CROSS-SUBTILE REGISTER DOUBLE-BUFFERED ds_reads:
// subtile s+1's fragment reads are issued DURING body s's MFMA phase, so
// the DS pipe works across the barrier and the post-barrier read ramp
// (~400-600cy of SIMD-dead time per body in round 5) disappears.
// Body s (cur regs C hold subtile s, read last body; buf b = s&3):
//   stage(s+3) [top: max DMA slack];
//   MFMA groups 0..FR/2-1 gated lgkm(FR-1-i) on C;
//   vmcnt(2*VMN)  -> forces stage(s+1) complete (issued 2.3 bodies ago);
//   issue nxt first half: B[0..FC-1], A[0..1] from buf (s+1)&3;
//   MFMA groups FR/2..FR-1 gated lgkm(FR+5-i)  [+6 for in-flight half];
//   issue nxt second half: A[2..FR-1];  s_barrier.
// Final gate (lgkm(6), cur_rem=0) drains all buf-s reads pre-barrier ->
// stage(s+4) (next body top) may overwrite buf s&3: race-free.
// Tail stages wrap mod NS (NS%4==0 keeps buf index); wrapped data unused.
// After the loop: lgkmcnt(0) so dangling async reads can't clobber
// epilogue registers reusing the dead fragment VGPRs.
// LDS: [row][32] bf16 rows (64B), 16B chunk swizzle phys = chunk ^
// (((row&15)>>1)&3); staged linearly via pre-swizzled per-lane global src.
// Requires: M%256==0, N%BN==0, K%128==0.
// ---------------------------------------------------------------------------
#define BODY(bc_, bn_, sw_, AC, BC, AN, BNX)                                  \
  {                                                                           \
    stageA(sw_);                                                              \
    stageB(sw_);                                                              \
    __builtin_amdgcn_sched_barrier(0);                                        \
    __builtin_amdgcn_s_setprio(1);                                            \
    mfma_gr<0, FR / 2, FR, FC, FR - 1>(AC, BC, acc);                          \
    __builtin_amdgcn_s_setprio(0);                                            \
    vmwait<2 * VMN>();                                                        \
    __builtin_amdgcn_sched_barrier(0);                                        \
    lds_cptr paN = sA3 + (bn_) * (256 * 32) + aoff;                           \
    lds_cptr pbN = sB3 + (bn_) * (BN * 32) + boff;                            \
    ldsr_rng<0, FC>(BNX, pbN);                                                \
    ldsr_rng<0, 2>(AN, paN);                                                  \
    __builtin_amdgcn_s_setprio(1);                                            \
    mfma_gr<FR / 2, FR, FR, FC, FR + 5>(AC, BC, acc);                         \
    __builtin_amdgcn_s_setprio(0);                                            \
    ldsr_rng<2, FR>(AN, paN);                                                 \
    __builtin_amdgcn_s_barrier();                                             \
  }

template <int BN, int WM, int WN, bool SWISH>
__global__ __launch_bounds__(512, 2) void gemm_bt8(
    const bf16_t* __restrict__ A, const bf16_t* __restrict__ B,
    const float* __restrict__ bias, void* __restrict__ Cout,
    int M, int N, int K, int XW, int px, int py) {
  constexpr int BM = 256;
  constexpr int WR = BM / WM;      // wave rows
  constexpr int WC = BN / WN;      // wave cols
  constexpr int FR = WR / 16;      // frag rows per wave (8 or 4)
  constexpr int FC = WC / 16;      // frag cols per wave (4)
  constexpr int ACALLS = BM / 128;       // gload calls per A subtile (2)
  constexpr int BCALLS = BN / 128;       // 2 (BN=256) or 1 (BN=128)
  constexpr int VMN = ACALLS + BCALLS;   // gload instrs per subtile stage

  const int tid = threadIdx.x;
  const int wave = tid >> 6;
  const int lane = tid & 63;

  // ---- XCD-aware block swizzle (grid % 8 == 0 in both uses) ----
  const int bid = blockIdx.x;
  const int xcd = bid & 7;
  const int idx = bid >> 3;
  const int cx = xcd % XW;
  const int cy = xcd / XW;
  const int bx = cx * px + idx % px;
  const int by = cy * py + idx / px;
  const int tileM = by * BM;
  const int tileN = bx * BN;

  __shared__ __align__(16) bf16_t sA[4 * 256 * 32];
  __shared__ __align__(16) bf16_t sB[4 * BN * 32];
  lds_cptr sA3 = (lds_cptr)sA;
  lds_cptr sB3 = (lds_cptr)sB;

  // ---- staging geometry: one call = 512 thr x 16B = 128 rows x 32 cols ----
  // lane -> row lane>>2, phys chunk lane&3 (linear LDS);
  // fetches GLOBAL chunk (lane&3) ^ ((lane>>3)&3)  [= chunk ^ ((row&15)>>1)&3]
  const int srow = (wave << 4) + (lane >> 2);              // 0..127
  const int sgc = ((lane & 3) ^ ((lane >> 3) & 3)) << 3;   // 0..24, global col
  const bf16_t* gA = A + (size_t)(tileM + srow) * K + sgc;
  const bf16_t* gB = B + (size_t)(tileN + srow) * K + sgc;
  bf16_t* lA = sA + (wave << 9);  // wave-uniform LDS base (wave*16 rows)
  bf16_t* lB = sB + (wave << 9);

  auto stageA = [&](int s) {
    bf16_t* l = lA + (s & 3) * (256 * 32);
    const bf16_t* g = gA + s * 32;
#pragma unroll
    for (int c = 0; c < ACALLS; ++c)
      gload_lds16(g + (size_t)(c * 128) * K, l + c * 128 * 32);
  };
  auto stageB = [&](int s) {
    bf16_t* l = lB + (s & 3) * (BN * 32);
    const bf16_t* g = gB + s * 32;
#pragma unroll
    for (int c = 0; c < BCALLS; ++c)
      gload_lds16(g + (size_t)(c * 128) * K, l + c * 128 * 32);
  };

  // ---- fragment read offsets (within one buffer, elements) ----
  const int wr = wave / WN;
  const int wc = wave % WN;
  const int fr = lane & 15;
  const int pc = (lane >> 4) ^ ((fr >> 1) & 3);  // swizzled phys chunk
  const int aoff = (wr * WR + fr) * 32 + pc * 8;
  const int boff = (wc * WC + fr) * 32 + pc * 8;

  f32x4 acc[FR][FC] = {};
  bf16x8 aR0[FR], bR0[FC], aR1[FR], bR1[FC];

  const int NS = K >> 5;  // 32-wide K subtiles; NS % 4 == 0

  // ---- prologue: stage 0,1,2; force 0 complete; sync; preload batch 0 ----
  stageA(0); stageB(0);
  stageA(1); stageB(1);
  stageA(2); stageB(2);
  vmwait<2 * VMN>();
  __builtin_amdgcn_s_barrier();
  __builtin_amdgcn_sched_barrier(0);
  ldsr_rng<0, FC>(bR0, sB3 + boff);
  ldsr_rng<0, FR>(aR0, sA3 + aoff);

  // ---- main loop: 4 subtiles per iteration, regs alternate R0/R1 ----
  for (int os = 0; os < NS; os += 4) {
    int w0 = os + 3;     if (w0 >= NS) w0 -= NS;
    int w1 = os + 4;     if (w1 >= NS) w1 -= NS;
    int w2 = os + 5;     if (w2 >= NS) w2 -= NS;
    int w3 = os + 6;     if (w3 >= NS) w3 -= NS;
    BODY(0, 1, w0, aR0, bR0, aR1, bR1)
    BODY(1, 2, w1, aR1, bR1, aR0, bR0)
    BODY(2, 3, w2, aR0, bR0, aR1, bR1)
    BODY(3, 0, w3, aR1, bR1, aR0, bR0)
  }
  lgkmwait<0>();  // drain dangling nxt reads before regs are reused
  __builtin_amdgcn_sched_barrier(0);

  // ---- epilogue: C/D layout col = lane&15, row = (lane>>4)*4 + reg ----
  // j INNERMOST: stores filling one cache line are adjacent so L2 merges
  // (round-5: WRITE_SIZE dropped to the ideal 64 MB).
  const int cRow0 = tileM + wr * WR + ((lane >> 4) << 2);
  const int cCol0 = tileN + wc * WC + (lane & 15);
  float bv[FC];
#pragma unroll
  for (int j = 0; j < FC; ++j) bv[j] = bias[cCol0 + j * 16];
#pragma unroll
  for (int i = 0; i < FR; ++i) {
#pragma unroll
    for (int r = 0; r < 4; ++r) {
      const size_t row = (size_t)(cRow0 + i * 16 + r);
#pragma unroll
      for (int j = 0; j < FC; ++j) {
        float h = acc[i][j][r] + bv[j];
        if constexpr (SWISH) {
          float h3 = h * h * h;
          float sw = h * (0.5f + 0.25f * h - 0.0208f * h3);
          ((bf16_t*)Cout)[row * N + cCol0 + j * 16] = (bf16_t)sw;
        } else {
          ((float*)Cout)[row * N + cCol0 + j * 16] = h;
        }
      }
    }
  }
}

// ---------------------------------------------------------------------------
// launch
// ---------------------------------------------------------------------------
extern "C" void kernel_launch(void* const* d_in, const int* in_sizes, int n_in,
                              void* d_out, int out_size, void* d_ws,
                              size_t ws_size, hipStream_t stream) {
  const float* X  = (const float*)d_in[0];  // [B,S,D] = [M,D]
  const float* W1 = (const float*)d_in[1];  // [F,D]
  const float* b1 = (const float*)d_in[2];  // [F]
  const float* W2 = (const float*)d_in[3];  // [D,F]
  const float* b2 = (const float*)d_in[4];  // [D]
  float* out = (float*)d_out;               // [M,D]

  const int F = in_sizes[2];      // 4096
  const int D = in_sizes[4];      // 1024
  const int M = in_sizes[0] / D;  // 8192

  // workspace layout (bf16): Xb[M*D] | W1b[F*D] | W2b[D*F] | SW[M*F]
  bf16_t* Xb  = (bf16_t*)d_ws;
  bf16_t* W1b = Xb + (size_t)M * D;
  bf16_t* W2b = W1b + (size_t)F * D;
  bf16_t* SW  = W2b + (size_t)D * F;

  const int nX = (M * D) / 8, nW1 = (F * D) / 8, nW2 = (D * F) / 8;
  const int nTot = nX + nW1 + nW2;
  cast3_f32_to_bf16<<<(nTot + 255) / 256, 256, 0, stream>>>(
      X, Xb, nX, W1, W1b, nW1, W2, W2b, nW2);

  // GEMM1: SW[M,F] = swish(Xb[M,D] @ W1b[F,D]^T + b1)   (bf16 out)
  // 256x256 tiles: gx = F/256 = 16, gy = M/256 = 32; XCDs as 2x4 -> 8x8 patch
  {
    const int gx = F / 256, gy = M / 256;
    const int XW = 2, XH = 4;
    const int px = gx / XW, py = gy / XH;
    gemm_bt8<256, 2, 4, true><<<gx * gy, 512, 0, stream>>>(
        Xb, W1b, b1, (void*)SW, M, F, D, XW, px, py);
  }

  // GEMM2: out[M,D] = SW[M,F] @ W2b[D,F]^T + b2         (fp32 out)
  // 256x128 tiles: gx = D/128 = 8, gy = M/256 = 32; XCDs as 1x8 -> 8x4 patch
  {
    const int gx = D / 128, gy = M / 256;
    const int XW = 1, XH = 8;
    const int px = gx / XW, py = gy / XH;
    gemm_bt8<128, 4, 2, false><<<gx * gy, 512, 0, stream>>>(
        SW, W2b, b2, (void*)out, M, D, F, XW, px, py);
  }
}